// Round 5
// baseline (713.778 us; speedup 1.0000x reference)
//
#include <hip/hip_runtime.h>
#include <hip/hip_cooperative_groups.h>
#include <math.h>

#define BB 8
#define TT 4096
#define DDIM 512
#define KK 4096
#define NN (BB*TT)
#define EPS 0.035f
#define CMAX 16384

namespace cg = cooperative_groups;

typedef __attribute__((ext_vector_type(8))) short bf16x8;
typedef __attribute__((ext_vector_type(4))) float f32x4;

__device__ __forceinline__ void async16(void* lds, const void* g) {
  __builtin_amdgcn_global_load_lds((const __attribute__((address_space(1))) void*)g,
                                   (__attribute__((address_space(3))) void*)lds, 16, 0, 0);
}

__device__ __forceinline__ unsigned pk_bf16(float a, float b) {
  unsigned ua = __float_as_uint(a); ua += 0x7FFFu + ((ua >> 16) & 1u);
  unsigned ub = __float_as_uint(b); ub += 0x7FFFu + ((ub >> 16) & 1u);
  return (ua >> 16) | (ub & 0xFFFF0000u);
}

// ---------- fused prep: bf16 convert + row stats for BOTH inputs, zero cnt ----------
__global__ __launch_bounds__(256) void prep_kernel(const float* __restrict__ x,
                                                   const float* __restrict__ embed,
                                                   short* __restrict__ xb,
                                                   short* __restrict__ eb,
                                                   float* __restrict__ inv2,
                                                   float* __restrict__ esq,
                                                   int* __restrict__ cnt) {
  if (blockIdx.x == 0 && threadIdx.x == 0) *cnt = 0;
  const float* src; short* dst; float* outv; int r; int mode;
  if (blockIdx.x < KK / 4) {
    src = embed; dst = eb; outv = esq; mode = 0;
    r = blockIdx.x * 4 + (threadIdx.x >> 6);
  } else {
    src = x; dst = xb; outv = inv2; mode = 1;
    r = (blockIdx.x - KK / 4) * 4 + (threadIdx.x >> 6);
  }
  int lane = threadIdx.x & 63;
  const float4* row4 = (const float4*)(src + (size_t)r * DDIM);
  float4 v0 = row4[lane];
  float4 v1 = row4[lane + 64];
  uint2 p0, p1;
  p0.x = pk_bf16(v0.x, v0.y); p0.y = pk_bf16(v0.z, v0.w);
  p1.x = pk_bf16(v1.x, v1.y); p1.y = pk_bf16(v1.z, v1.w);
  *(uint2*)(dst + (size_t)r * DDIM + lane * 4) = p0;
  *(uint2*)(dst + (size_t)r * DDIM + 256 + lane * 4) = p1;
  float ss = v0.x*v0.x + v0.y*v0.y + v0.z*v0.z + v0.w*v0.w
           + v1.x*v1.x + v1.y*v1.y + v1.z*v1.z + v1.w*v1.w;
  #pragma unroll
  for (int off = 32; off; off >>= 1) ss += __shfl_down(ss, off);
  if (lane == 0) outv[r] = mode ? 2.0f / fmaxf(sqrtf(ss), 1e-12f) : ss;
}

// ---------- main MFMA pass: 128x128 tile (round-2 proven structure), 3 waves/EU ----------
// grid 1024: bid&255 = m-block (128 rows), bid>>8 = k-quarter (1024 codes)
__global__ __launch_bounds__(256, 3) void vq_mfma(const short* __restrict__ xb,
                                                  const short* __restrict__ eb,
                                                  const float* __restrict__ esq,
                                                  const float* __restrict__ inv2,
                                                  float4* __restrict__ top2) {
  __shared__ short As[128 * 64];
  __shared__ short Bs[128 * 64];
  __shared__ float rS1[2][128];
  __shared__ float rS2[2][128];
  __shared__ int   rI1[2][128];

  const int tid = threadIdx.x;
  const int lane = tid & 63;
  const int w = tid >> 6;
  const int wr = w >> 1, wc = w & 1;
  const int q = lane >> 4, c16 = lane & 15;

  const int mb = blockIdx.x & 255;
  const int kq = blockIdx.x >> 8;
  const int n0 = mb * 128;
  const int kbase = kq * 1024;

  // staging: lane fills LDS row (w*32+i*8+(lane>>3)), 16B chunk (lane&7);
  // global column chunk XOR-swizzled by (lane>>3) -> conflict-free frag reads
  const int srow = w * 32 + (lane >> 3);
  const int scol = ((lane & 7) ^ (lane >> 3)) * 8;
  const short* gA = xb + (size_t)(n0 + srow) * DDIM + scol;

  float s1[16], s2v[16];
  int   i1[16];
  #pragma unroll
  for (int s = 0; s < 16; ++s) { s1[s] = -3e38f; s2v[s] = -3e38f; i1[s] = 0; }

  f32x4 inv4[4];
  #pragma unroll
  for (int ti = 0; ti < 4; ++ti)
    inv4[ti] = *(const f32x4*)&inv2[n0 + wr * 64 + ti * 16 + q * 4];

  for (int c = 0; c < 8; ++c) {
    const int k0c = kbase + c * 128;
    const short* gB = eb + (size_t)(k0c + srow) * DDIM + scol;
    f32x4 acc[4][4];
    #pragma unroll
    for (int ti = 0; ti < 4; ++ti)
      #pragma unroll
      for (int tj = 0; tj < 4; ++tj) acc[ti][tj] = (f32x4){0.f, 0.f, 0.f, 0.f};

    for (int d0 = 0; d0 < DDIM; d0 += 64) {
      #pragma unroll
      for (int i = 0; i < 4; ++i) {
        async16(As + (w * 32 + i * 8) * 64, gA + (size_t)i * 8 * DDIM + d0);
        async16(Bs + (w * 32 + i * 8) * 64, gB + (size_t)i * 8 * DDIM + d0);
      }
      __syncthreads();
      #pragma unroll
      for (int ks = 0; ks < 2; ++ks) {
        const int ko = (((ks << 2) | q) ^ (lane & 7)) << 3;  // swizzled k-chunk
        bf16x8 af[4], bf[4];
        #pragma unroll
        for (int ti = 0; ti < 4; ++ti)
          af[ti] = *(const bf16x8*)&As[(wr * 64 + ti * 16 + c16) * 64 + ko];
        #pragma unroll
        for (int tj = 0; tj < 4; ++tj)
          bf[tj] = *(const bf16x8*)&Bs[(wc * 64 + tj * 16 + c16) * 64 + ko];
        #pragma unroll
        for (int ti = 0; ti < 4; ++ti)
          #pragma unroll
          for (int tj = 0; tj < 4; ++tj)
            acc[ti][tj] = __builtin_amdgcn_mfma_f32_16x16x32_bf16(af[ti], bf[tj], acc[ti][tj], 0, 0, 0);
      }
      __syncthreads();
    }
    // epilogue: score = acc*inv2 - esq, update per-row top-2
    #pragma unroll
    for (int tj = 0; tj < 4; ++tj) {
      const int col = k0c + wc * 64 + tj * 16 + c16;
      const float nes = -esq[col];
      #pragma unroll
      for (int ti = 0; ti < 4; ++ti)
        #pragma unroll
        for (int r = 0; r < 4; ++r) {
          int slot = ti * 4 + r;
          float sc = fmaf(acc[ti][tj][r], inv4[ti][r], nes);
          float mn = fminf(sc, s1[slot]);
          s2v[slot] = fmaxf(s2v[slot], mn);
          if (sc > s1[slot]) { s1[slot] = sc; i1[slot] = col; }
        }
    }
  }

  // reduce across the 16 lanes sharing each row
  #pragma unroll
  for (int slot = 0; slot < 16; ++slot) {
    float a1 = s1[slot], a2 = s2v[slot]; int ai = i1[slot];
    #pragma unroll
    for (int off = 1; off < 16; off <<= 1) {
      float b1 = __shfl_xor(a1, off);
      float b2 = __shfl_xor(a2, off);
      int   bi = __shfl_xor(ai, off);
      float mn = fminf(a1, b1);
      a2 = fmaxf(fmaxf(a2, b2), mn);
      if (b1 > a1 || (b1 == a1 && bi < ai)) { a1 = b1; ai = bi; }
    }
    if (c16 == 0) {
      int row = wr * 64 + (slot >> 2) * 16 + q * 4 + (slot & 3);
      rS1[wc][row] = a1; rS2[wc][row] = a2; rI1[wc][row] = ai;
    }
  }
  __syncthreads();
  if (tid < 128) {
    float a1 = rS1[0][tid], a2 = rS2[0][tid]; int ai = rI1[0][tid];
    float b1 = rS1[1][tid], b2 = rS2[1][tid]; int bi = rI1[1][tid];
    float mn = fminf(a1, b1);
    a2 = fmaxf(fmaxf(a2, b2), mn);
    if (b1 > a1 || (b1 == a1 && bi < ai)) { a1 = b1; ai = bi; }
    top2[(size_t)kq * NN + n0 + tid] = make_float4(a1, __int_as_float(ai), a2, 0.f);
  }
}

// ---------- cooperative tail: finalize -> (gather + exact rescore) -> fixup ----------
// grid 512 x 256, one launch, grid.sync between phases
__global__ __launch_bounds__(256) void tail_kernel(const float* __restrict__ x,
                                                   const float* __restrict__ embed,
                                                   const float* __restrict__ esq,
                                                   const float* __restrict__ inv2,
                                                   const float4* __restrict__ top2,
                                                   float* __restrict__ out_ind,
                                                   float* __restrict__ out_q,
                                                   int* __restrict__ list,
                                                   int* __restrict__ cnt,
                                                   float2* __restrict__ exact) {
  cg::grid_group grid = cg::this_grid();
  __shared__ __align__(16) char shraw[33664];
  const int tid = threadIdx.x;
  const int bid = blockIdx.x;
  const int lane = tid & 63, w = tid >> 6;

  // ---- P1 finalize: merge 4 k-quarters, write bf16 idx, build small-margin list ----
  if (bid < NN / 256) {
    int row = bid * 256 + tid;
    float a1 = -3e38f, a2 = -3e38f; int ai = 0;
    #pragma unroll
    for (int kq = 0; kq < 4; ++kq) {
      float4 t = top2[(size_t)kq * NN + row];
      float b1 = t.x, b2 = t.z; int bi = __float_as_int(t.y);
      float mn = fminf(a1, b1);
      a2 = fmaxf(fmaxf(a2, b2), mn);
      if (b1 > a1 || (b1 == a1 && bi < ai)) { a1 = b1; ai = bi; }
    }
    out_ind[row] = (float)ai;
    if (a1 - a2 < EPS) {
      int p = atomicAdd(cnt, 1);
      if (p < CMAX) list[p] = row;
    }
  }
  grid.sync();

  // ---- P2a gather + transpose for ALL rows using bf16 indices ----
  {
    int* lidx = (int*)shraw;
    float* trans = (float*)(shraw + 256);
    const int n0 = bid * 64;
    if (tid < 64) lidx[tid] = (int)out_ind[n0 + tid];
    __syncthreads();
    const int bb = n0 >> 12;
    const int t0 = n0 & (TT - 1);
    for (int d0 = 0; d0 < DDIM; d0 += 64) {
      if (d0) __syncthreads();
      #pragma unroll
      for (int qq = 0; qq < 16; ++qq) {
        int tt2 = w * 16 + qq;
        int e = lidx[tt2];
        trans[lane * 65 + tt2] = embed[(size_t)e * DDIM + d0 + lane];
      }
      __syncthreads();
      #pragma unroll
      for (int qq = 0; qq < 4; ++qq) {
        int dl = (tid >> 4) * 4 + qq;
        int t4 = (tid & 15) * 4;
        float4 o;
        o.x = trans[dl * 65 + t4 + 0];
        o.y = trans[dl * 65 + t4 + 1];
        o.z = trans[dl * 65 + t4 + 2];
        o.w = trans[dl * 65 + t4 + 3];
        *(float4*)&out_q[((size_t)bb * DDIM + d0 + dl) * TT + t0 + t4] = o;
      }
    }
  }

  // ---- P2b exact fp32 rescore of flagged rows (16 rows staged in LDS) ----
  {
    float* xr    = (float*)shraw;             // 16*512*4 = 32768
    float* xiv   = (float*)(shraw + 32768);   // 64
    int*   rid   = (int*)(shraw + 32832);     // 64
    float* red_s = (float*)(shraw + 32896);   // 256
    int*   red_i = (int*)(shraw + 33152);     // 256
    int n = atomicAdd(cnt, 0); if (n > CMAX) n = CMAX;
    const int kc = bid >> 5;     // 16 code chunks of 256
    const int slot = bid & 31;   // 32 row-tile slots
    const int code = kc * 256 + tid;
    const float4* erow = (const float4*)&embed[(size_t)code * DDIM];
    const float nes = -esq[code];
    for (int tile = slot; tile * 16 < n; tile += 32) {
      __syncthreads();
      if (tid < 16) {
        int pos = tile * 16 + tid;
        int row = (pos < n) ? list[pos] : list[0];
        rid[tid] = row;
        xiv[tid] = inv2[row];
      }
      __syncthreads();
      #pragma unroll
      for (int i = 0; i < 8; ++i) {
        int idx = tid + i * 256;
        int rl = idx >> 7, d4 = idx & 127;
        ((float4*)(xr + rl * DDIM))[d4] = *(const float4*)&x[(size_t)rid[rl] * DDIM + d4 * 4];
      }
      __syncthreads();
      float acc[16];
      #pragma unroll
      for (int r = 0; r < 16; ++r) acc[r] = 0.f;
      for (int d4 = 0; d4 < 128; ++d4) {
        float4 e4 = erow[d4];
        #pragma unroll
        for (int r = 0; r < 16; ++r) {
          float4 x4 = ((const float4*)(xr + r * DDIM))[d4];
          acc[r] += e4.x * x4.x + e4.y * x4.y + e4.z * x4.z + e4.w * x4.w;
        }
      }
      #pragma unroll
      for (int r = 0; r < 16; ++r) {
        float bs = fmaf(acc[r], xiv[r], nes);
        int bi = code;
        #pragma unroll
        for (int off = 1; off < 64; off <<= 1) {
          float b1 = __shfl_xor(bs, off);
          int   b2 = __shfl_xor(bi, off);
          if (b1 > bs || (b1 == bs && b2 < bi)) { bs = b1; bi = b2; }
        }
        if (lane == 0) { red_s[w * 16 + r] = bs; red_i[w * 16 + r] = bi; }
      }
      __syncthreads();
      if (tid < 16) {
        float bs = red_s[tid]; int bi = red_i[tid];
        #pragma unroll
        for (int ww = 1; ww < 4; ++ww) {
          float b1 = red_s[ww * 16 + tid]; int b2 = red_i[ww * 16 + tid];
          if (b1 > bs || (b1 == bs && b2 < bi)) { bs = b1; bi = b2; }
        }
        int pos = tile * 16 + tid;
        if (pos < n) exact[(size_t)pos * 16 + kc] = make_float2(bs, (float)bi);
      }
    }
  }
  grid.sync();

  // ---- P3 fixup: rows whose exact argmax differs from bf16 pick ----
  {
    int n = atomicAdd(cnt, 0); if (n > CMAX) n = CMAX;
    int gw = bid * 4 + w;
    for (int i = gw; i < n; i += 512 * 4) {
      int row = list[i];
      float bs = -3e38f; int bi = 0x7fffffff;
      if (lane < 16) {
        float2 t = exact[(size_t)i * 16 + lane];
        bs = t.x; bi = (int)t.y;
      }
      #pragma unroll
      for (int off = 1; off < 16; off <<= 1) {
        float b1 = __shfl_xor(bs, off);
        int   b2 = __shfl_xor(bi, off);
        if (b1 > bs || (b1 == bs && b2 < bi)) { bs = b1; bi = b2; }
      }
      bs = __shfl(bs, 0); bi = __shfl(bi, 0);
      int old = (int)out_ind[row];
      if (bi != old) {
        if (lane == 0) out_ind[row] = (float)bi;
        int b = row >> 12, t = row & (TT - 1);
        for (int d = lane; d < DDIM; d += 64)
          out_q[((size_t)b * DDIM + d) * TT + t] = embed[(size_t)bi * DDIM + d];
      }
    }
  }
}

extern "C" void kernel_launch(void* const* d_in, const int* in_sizes, int n_in,
                              void* d_out, int out_size, void* d_ws, size_t ws_size,
                              hipStream_t stream) {
  const float* x     = (const float*)d_in[0];
  const float* embed = (const float*)d_in[1];
  char* ws = (char*)d_ws;
  short* xb      = (short*)(ws);                 // 33,554,432 B
  short* eb      = (short*)(ws + 33554432);      //  4,194,304 B
  float* esq     = (float*)(ws + 37748736);      //     16,384 B
  float* inv2    = (float*)(ws + 37765120);      //    131,072 B
  float4* top2   = (float4*)(ws + 37896192);     //  2,097,152 B
  int* list      = (int*)(ws + 39993344);        //     65,536 B
  float2* exact  = (float2*)(ws + 40058880);     //  2,097,152 B
  int* cnt       = (int*)(ws + 42156032);        //          4 B

  float* out_ind = (float*)d_out;
  float* out_q   = out_ind + NN;

  prep_kernel<<<KK / 4 + NN / 4, 256, 0, stream>>>(x, embed, xb, eb, inv2, esq, cnt);
  vq_mfma<<<1024, 256, 0, stream>>>(xb, eb, esq, inv2, top2);

  void* args[] = {(void*)&x, (void*)&embed, (void*)&esq, (void*)&inv2,
                  (void*)&top2, (void*)&out_ind, (void*)&out_q,
                  (void*)&list, (void*)&cnt, (void*)&exact};
  hipLaunchCooperativeKernel((const void*)tail_kernel, dim3(512), dim3(256),
                             args, 0, stream);
}

// Round 6
// 343.217 us; speedup vs baseline: 2.0797x; 2.0797x over previous
//
#include <hip/hip_runtime.h>
#include <math.h>

#define BB 8
#define TT 4096
#define DDIM 512
#define KK 4096
#define NN (BB*TT)
#define EPS 0.035f
#define LCAP 2048

typedef __attribute__((ext_vector_type(8))) short bf16x8;
typedef __attribute__((ext_vector_type(4))) float f32x4;

__device__ __forceinline__ void async16(void* lds, const void* g) {
  __builtin_amdgcn_global_load_lds((const __attribute__((address_space(1))) void*)g,
                                   (__attribute__((address_space(3))) void*)lds, 16, 0, 0);
}

__device__ __forceinline__ unsigned pk_bf16(float a, float b) {
  unsigned ua = __float_as_uint(a); ua += 0x7FFFu + ((ua >> 16) & 1u);
  unsigned ub = __float_as_uint(b); ub += 0x7FFFu + ((ub >> 16) & 1u);
  return (ua >> 16) | (ub & 0xFFFF0000u);
}

// ---------- fused prep: bf16 convert + row stats for BOTH inputs ----------
__global__ __launch_bounds__(256) void prep_kernel(const float* __restrict__ x,
                                                   const float* __restrict__ embed,
                                                   short* __restrict__ xb,
                                                   short* __restrict__ eb,
                                                   float* __restrict__ inv2,
                                                   float* __restrict__ esq) {
  const float* src; short* dst; float* outv; int r; int mode;
  if (blockIdx.x < KK / 4) {
    src = embed; dst = eb; outv = esq; mode = 0;
    r = blockIdx.x * 4 + (threadIdx.x >> 6);
  } else {
    src = x; dst = xb; outv = inv2; mode = 1;
    r = (blockIdx.x - KK / 4) * 4 + (threadIdx.x >> 6);
  }
  int lane = threadIdx.x & 63;
  const float4* row4 = (const float4*)(src + (size_t)r * DDIM);
  float4 v0 = row4[lane];
  float4 v1 = row4[lane + 64];
  uint2 p0, p1;
  p0.x = pk_bf16(v0.x, v0.y); p0.y = pk_bf16(v0.z, v0.w);
  p1.x = pk_bf16(v1.x, v1.y); p1.y = pk_bf16(v1.z, v1.w);
  *(uint2*)(dst + (size_t)r * DDIM + lane * 4) = p0;
  *(uint2*)(dst + (size_t)r * DDIM + 256 + lane * 4) = p1;
  float ss = v0.x*v0.x + v0.y*v0.y + v0.z*v0.z + v0.w*v0.w
           + v1.x*v1.x + v1.y*v1.y + v1.z*v1.z + v1.w*v1.w;
  #pragma unroll
  for (int off = 32; off; off >>= 1) ss += __shfl_down(ss, off);
  if (lane == 0) outv[r] = mode ? 2.0f / fmaxf(sqrtf(ss), 1e-12f) : ss;
}

// ---------- main MFMA pass: round-2 proven 128x128 structure at (256,2);
// emits per-256-code-chunk top-2 planes instead of global top-2 ----------
// grid 1024: bid&255 = m-block (128 rows), bid>>8 = k-quarter (1024 codes)
__global__ __launch_bounds__(256, 2) void vq_mfma(const short* __restrict__ xb,
                                                  const short* __restrict__ eb,
                                                  const float* __restrict__ esq,
                                                  const float* __restrict__ inv2,
                                                  float* __restrict__ cts1,
                                                  float* __restrict__ cts2,
                                                  int* __restrict__ cti) {
  __shared__ short As[128 * 64];
  __shared__ short Bs[128 * 64];
  __shared__ float rS1[2][128];
  __shared__ float rS2[2][128];
  __shared__ int   rI1[2][128];

  const int tid = threadIdx.x;
  const int lane = tid & 63;
  const int w = tid >> 6;
  const int wr = w >> 1, wc = w & 1;
  const int q = lane >> 4, c16 = lane & 15;

  const int mb = blockIdx.x & 255;
  const int kq = blockIdx.x >> 8;
  const int n0 = mb * 128;
  const int kbase = kq * 1024;

  const int srow = w * 32 + (lane >> 3);
  const int scol = ((lane & 7) ^ (lane >> 3)) * 8;   // XOR swizzle: conflict-free frags
  const short* gA = xb + (size_t)(n0 + srow) * DDIM + scol;

  f32x4 inv4[4];
  #pragma unroll
  for (int ti = 0; ti < 4; ++ti)
    inv4[ti] = *(const f32x4*)&inv2[n0 + wr * 64 + ti * 16 + q * 4];

  for (int p = 0; p < 4; ++p) {          // p = 256-code chunk within quarter
    float cs1[16], cs2[16];
    int   ci1[16];
    #pragma unroll
    for (int s = 0; s < 16; ++s) { cs1[s] = -3e38f; cs2[s] = -3e38f; ci1[s] = 0; }

    for (int cc = 0; cc < 2; ++cc) {     // two 128-col sub-chunks
      const int c = p * 2 + cc;
      const int k0c = kbase + c * 128;
      const short* gB = eb + (size_t)(k0c + srow) * DDIM + scol;
      f32x4 acc[4][4];
      #pragma unroll
      for (int ti = 0; ti < 4; ++ti)
        #pragma unroll
        for (int tj = 0; tj < 4; ++tj) acc[ti][tj] = (f32x4){0.f, 0.f, 0.f, 0.f};

      for (int d0 = 0; d0 < DDIM; d0 += 64) {
        #pragma unroll
        for (int i = 0; i < 4; ++i) {
          async16(As + (w * 32 + i * 8) * 64, gA + (size_t)i * 8 * DDIM + d0);
          async16(Bs + (w * 32 + i * 8) * 64, gB + (size_t)i * 8 * DDIM + d0);
        }
        __syncthreads();
        #pragma unroll
        for (int ks = 0; ks < 2; ++ks) {
          const int ko = (((ks << 2) | q) ^ (lane & 7)) << 3;
          bf16x8 af[4], bf[4];
          #pragma unroll
          for (int ti = 0; ti < 4; ++ti)
            af[ti] = *(const bf16x8*)&As[(wr * 64 + ti * 16 + c16) * 64 + ko];
          #pragma unroll
          for (int tj = 0; tj < 4; ++tj)
            bf[tj] = *(const bf16x8*)&Bs[(wc * 64 + tj * 16 + c16) * 64 + ko];
          #pragma unroll
          for (int ti = 0; ti < 4; ++ti)
            #pragma unroll
            for (int tj = 0; tj < 4; ++tj)
              acc[ti][tj] = __builtin_amdgcn_mfma_f32_16x16x32_bf16(af[ti], bf[tj], acc[ti][tj], 0, 0, 0);
        }
        __syncthreads();
      }
      // epilogue: update per-chunk top-2
      #pragma unroll
      for (int tj = 0; tj < 4; ++tj) {
        const int col = k0c + wc * 64 + tj * 16 + c16;
        const float nes = -esq[col];
        #pragma unroll
        for (int ti = 0; ti < 4; ++ti)
          #pragma unroll
          for (int r = 0; r < 4; ++r) {
            int slot = ti * 4 + r;
            float sc = fmaf(acc[ti][tj][r], inv4[ti][r], nes);
            cs2[slot] = fmaxf(cs2[slot], fminf(sc, cs1[slot]));
            if (sc > cs1[slot]) { cs1[slot] = sc; ci1[slot] = col; }
          }
      }
    }
    // 16-lane reduce of chunk top-2, then cross-wave merge + plane write
    #pragma unroll
    for (int slot = 0; slot < 16; ++slot) {
      float a1 = cs1[slot], a2 = cs2[slot]; int ai = ci1[slot];
      #pragma unroll
      for (int off = 1; off < 16; off <<= 1) {
        float b1 = __shfl_xor(a1, off);
        float b2 = __shfl_xor(a2, off);
        int   bi = __shfl_xor(ai, off);
        float ns2 = fmaxf(fmaxf(a2, b2), fminf(a1, b1));
        if (b1 > a1 || (b1 == a1 && bi < ai)) { a1 = b1; ai = bi; }
        a2 = ns2;
      }
      if (c16 == 0) {
        int row = wr * 64 + (slot >> 2) * 16 + q * 4 + (slot & 3);
        rS1[wc][row] = a1; rS2[wc][row] = a2; rI1[wc][row] = ai;
      }
    }
    __syncthreads();
    if (tid < 128) {
      float a1 = rS1[0][tid], a2 = rS2[0][tid]; int ai = rI1[0][tid];
      float b1 = rS1[1][tid], b2 = rS2[1][tid]; int bi = rI1[1][tid];
      float ns2 = fmaxf(fmaxf(a2, b2), fminf(a1, b1));
      if (b1 > a1 || (b1 == a1 && bi < ai)) { a1 = b1; ai = bi; }
      size_t o = (size_t)(kq * 4 + p) * NN + n0 + tid;
      cts1[o] = a1; cts2[o] = ns2; cti[o] = ai;
    }
  }
}

// ---------- tail: merge chunk tops -> candidate fp32 rescore -> gather/transpose ----------
// grid 512, 64 rows per block
__global__ __launch_bounds__(256) void tail_kernel(const float* __restrict__ x,
                                                   const float* __restrict__ embed,
                                                   const float* __restrict__ esq,
                                                   const float* __restrict__ inv2,
                                                   const float* __restrict__ cts1,
                                                   const float* __restrict__ cts2,
                                                   const int* __restrict__ cti,
                                                   float* __restrict__ out_ind,
                                                   float* __restrict__ out_q) {
  __shared__ float ct_s1[16][64];
  __shared__ float ct_s2[16][64];
  __shared__ int   ct_i[16][64];
  __shared__ int   lidx[64];
  __shared__ unsigned long long pw[64];
  __shared__ int   list[LCAP];
  __shared__ int   lcnt;
  __shared__ float trans[64 * 65];

  const int tid = threadIdx.x;
  const int lane = tid & 63, wv = tid >> 6;
  const int n0 = blockIdx.x * 64;

  // P1: stage chunk-top planes (coalesced)
  #pragma unroll
  for (int i = 0; i < 4; ++i) {
    int ch = i * 4 + wv;
    size_t o = (size_t)ch * NN + n0 + lane;
    ct_s1[ch][lane] = cts1[o];
    ct_s2[ch][lane] = cts2[o];
    ct_i[ch][lane]  = cti[o];
  }
  if (tid == 0) lcnt = 0;
  __syncthreads();

  // P2: per-row merge; collect candidates for ambiguous rows
  if (tid < 64) {
    float a1 = -3e38f; int ai = 0x7FFFFFFF;
    #pragma unroll
    for (int ch = 0; ch < 16; ++ch) {
      float b1 = ct_s1[ch][tid]; int bi = ct_i[ch][tid];
      if (b1 > a1 || (b1 == a1 && bi < ai)) { a1 = b1; ai = bi; }
    }
    const float thr = a1 - EPS;
    int extra = 0;
    #pragma unroll
    for (int ch = 0; ch < 16; ++ch) {
      if (ct_s2[ch][tid] >= thr) extra++;
      else if (ct_s1[ch][tid] >= thr && ct_i[ch][tid] != ai) extra++;
    }
    if (extra == 0) {
      lidx[tid] = ai;                      // unambiguous: done
    } else {
      lidx[tid] = -1; pw[tid] = 0ull;
      int p = atomicAdd(&lcnt, 1);         // top1 itself
      if (p < LCAP) list[p] = (tid << 12) | ai;
      for (int ch = 0; ch < 16; ++ch) {
        if (ct_s2[ch][tid] >= thr) {       // hidden-code risk: whole 256-chunk
          int base = atomicAdd(&lcnt, 256);
          for (int k = 0; k < 256; ++k)
            if (base + k < LCAP) list[base + k] = (tid << 12) | (ch * 256 + k);
        } else if (ct_s1[ch][tid] >= thr && ct_i[ch][tid] != ai) {
          int pp = atomicAdd(&lcnt, 1);
          if (pp < LCAP) list[pp] = (tid << 12) | ct_i[ch][tid];
        }
      }
    }
  }
  __syncthreads();

  // P3: wave-per-candidate exact fp32 rescore, packed-u64 argmax (tie -> smaller idx)
  {
    int e = lcnt; if (e > LCAP) e = LCAP;
    for (int i = wv; i < e; i += 4) {
      int ent = list[i];
      int r = ent >> 12, code = ent & 4095;
      int grow = n0 + r;
      const float4* xp = (const float4*)&x[(size_t)grow * DDIM + lane * 8];
      const float4* ep = (const float4*)&embed[(size_t)code * DDIM + lane * 8];
      float4 xa = xp[0], xb4 = xp[1], ea = ep[0], eb4 = ep[1];
      float d = xa.x*ea.x + xa.y*ea.y + xa.z*ea.z + xa.w*ea.w
              + xb4.x*eb4.x + xb4.y*eb4.y + xb4.z*eb4.z + xb4.w*eb4.w;
      #pragma unroll
      for (int off = 1; off < 64; off <<= 1) d += __shfl_xor(d, off);
      if (lane == 0) {
        float sc = fmaf(d, inv2[grow], -esq[code]);
        unsigned u = __float_as_uint(sc);
        u = (u >> 31) ? ~u : (u | 0x80000000u);
        unsigned long long pk = ((unsigned long long)u << 32) | (unsigned)(~code);
        atomicMax(&pw[r], pk);
      }
    }
  }
  __syncthreads();

  // P4: resolve indices, write out_ind
  if (tid < 64) {
    int idx = lidx[tid];
    if (idx < 0) idx = (int)((~(unsigned)(pw[tid] & 0xFFFFFFFFull)) & 4095u);
    lidx[tid] = idx;
    out_ind[n0 + tid] = (float)idx;
  }
  __syncthreads();

  // P5: gather + transpose (proven round-2 pattern)
  const int bb = n0 >> 12;
  const int t0 = n0 & (TT - 1);
  for (int d0 = 0; d0 < DDIM; d0 += 64) {
    if (d0) __syncthreads();
    #pragma unroll
    for (int qq = 0; qq < 16; ++qq) {
      int tt2 = wv * 16 + qq;
      int e = lidx[tt2];
      trans[lane * 65 + tt2] = embed[(size_t)e * DDIM + d0 + lane];
    }
    __syncthreads();
    #pragma unroll
    for (int qq = 0; qq < 4; ++qq) {
      int dl = (tid >> 4) * 4 + qq;
      int t4 = (tid & 15) * 4;
      float4 o;
      o.x = trans[dl * 65 + t4 + 0];
      o.y = trans[dl * 65 + t4 + 1];
      o.z = trans[dl * 65 + t4 + 2];
      o.w = trans[dl * 65 + t4 + 3];
      *(float4*)&out_q[((size_t)bb * DDIM + d0 + dl) * TT + t0 + t4] = o;
    }
  }
}

extern "C" void kernel_launch(void* const* d_in, const int* in_sizes, int n_in,
                              void* d_out, int out_size, void* d_ws, size_t ws_size,
                              hipStream_t stream) {
  const float* x     = (const float*)d_in[0];
  const float* embed = (const float*)d_in[1];
  char* ws = (char*)d_ws;
  short* xb   = (short*)(ws);                 // 33,554,432 B
  short* eb   = (short*)(ws + 33554432);      //  4,194,304 B
  float* esq  = (float*)(ws + 37748736);      //     16,384 B
  float* inv2 = (float*)(ws + 37765120);      //    131,072 B
  float* cts1 = (float*)(ws + 37896192);      //  2,097,152 B
  float* cts2 = (float*)(ws + 39993344);      //  2,097,152 B
  int*   cti  = (int*)  (ws + 42090496);      //  2,097,152 B  (total 44.2 MB)

  float* out_ind = (float*)d_out;
  float* out_q   = out_ind + NN;

  prep_kernel<<<KK / 4 + NN / 4, 256, 0, stream>>>(x, embed, xb, eb, inv2, esq);
  vq_mfma<<<1024, 256, 0, stream>>>(xb, eb, esq, inv2, cts1, cts2, cti);
  tail_kernel<<<NN / 64, 256, 0, stream>>>(x, embed, esq, inv2, cts1, cts2, cti,
                                           out_ind, out_q);
}